// Round 1
// baseline (177.192 us; speedup 1.0000x reference)
//
#include <hip/hip_runtime.h>
#include <math.h>

// Problem dims (fixed by setup_inputs)
#define N_  8
#define C_  4
#define A_  180
#define R_  180
#define NC  (N_*C_)        // 32
#define AR  (A_*R_)        // 32400
#define WPA 3              // u64 words per angle bitmask (180 bits)

// ws layout (bytes)
#define OFF_MAX 0                       // float maxv[32]            (128 B)
#define OFF_B   128                     // u64 B[32][180][3]         (138240 B)
#define OFF_D   (128 + 138240)          // u64 D[32][180][3]         (138240 B)
#define OFF_TBL (OFF_D + 138240)        // float ct[180] st[180] rphys[180] misc[4]
#define WS_BYTES (OFF_TBL + (3*A_ + 4)*4)

typedef unsigned long long u64;

// ---------------------------------------------------------------------------
// Kernel A: per-(n,c) global max (blocks 0..31) + trig/rho tables (block 32)
// ---------------------------------------------------------------------------
__global__ __launch_bounds__(256) void precompute_kernel(
    const float* __restrict__ hm,
    const int* __restrict__ Hp, const int* __restrict__ Wp,
    float* __restrict__ maxv, float* __restrict__ tbl) {
  int b = blockIdx.x;
  if (b < NC) {
    const float* p = hm + (size_t)b * AR;
    float m = -INFINITY;
    for (int i = threadIdx.x; i < AR; i += 256) m = fmaxf(m, p[i]);
    for (int off = 32; off; off >>= 1) m = fmaxf(m, __shfl_down(m, off, 64));
    __shared__ float sm[4];
    if ((threadIdx.x & 63) == 0) sm[threadIdx.x >> 6] = m;
    __syncthreads();
    if (threadIdx.x == 0) {
      maxv[b] = fmaxf(fmaxf(sm[0], sm[1]), fmaxf(sm[2], sm[3]));
    }
  } else {
    int t = threadIdx.x;
    int H = Hp[0], W = Wp[0];
    double max_rho = sqrt((double)(W/2)*(double)(W/2) + (double)(H/2)*(double)(H/2));
    float drho = (float)(2.0 * max_rho / (double)(R_ - 1));
    if (t < A_) {
      // theta = f32(a) * f32(pi/A)  — matches jnp.arange(A,f32)*(np.pi/A)
      float theta = __fmul_rn((float)t, (float)(3.14159265358979323846 / (double)A_));
      tbl[t]        = (float)cos((double)theta);   // correctly-rounded f32 cos
      tbl[A_ + t]   = (float)sin((double)theta);
      // r_phys = (f32(r) - 89.5) * f32(delta_rho)
      tbl[2*A_ + t] = __fmul_rn(__fsub_rn((float)t, (float)((R_-1)*0.5)), drho);
    }
    if (t == 0) {
      tbl[3*A_ + 0] = drho;
      tbl[3*A_ + 1] = 1.0f / drho;
      tbl[3*A_ + 2] = (float)((W - 1) * 0.5);   // 127.5
      tbl[3*A_ + 3] = (float)((H - 1) * 0.5);
    }
  }
}

// ---------------------------------------------------------------------------
// Kernel B: peak detection -> bitmasks B (exact peaks) and D (dilated [-2,+1])
// peak := hm > 0.5*max  AND  no 3x3 neighbor strictly greater (== maxpool)
// ---------------------------------------------------------------------------
__global__ __launch_bounds__(256) void peaks_kernel(
    const float* __restrict__ hm, const float* __restrict__ maxv,
    u64* __restrict__ Bm, u64* __restrict__ Dm) {
  int idx = blockIdx.x * 256 + threadIdx.x;
  if (idx >= NC * AR) return;
  int nc  = idx / AR;
  int rem = idx - nc * AR;
  float val = hm[idx];
  float thr = 0.5f * maxv[nc];
  if (!(val > thr)) return;               // ~99% early-out
  int a = rem / R_;
  int r = rem - a * R_;
  const float* base = hm + (size_t)nc * AR;
  bool peak = true;
  for (int da = -1; da <= 1 && peak; ++da) {
    int aa = a + da;
    if (aa < 0 || aa >= A_) continue;     // SAME pad with -inf
    for (int dr = -1; dr <= 1; ++dr) {
      if (da == 0 && dr == 0) continue;
      int rr = r + dr;
      if (rr < 0 || rr >= R_) continue;
      if (base[aa * R_ + rr] > val) { peak = false; break; }
    }
  }
  if (!peak) return;
  int w = (nc * A_ + a) * WPA;
  atomicOr(&Bm[w + (r >> 6)], 1ull << (r & 63));
  int clo = r - 2 < 0 ? 0 : r - 2;
  int chi = r + 1 > R_ - 1 ? R_ - 1 : r + 1;
  for (int c = clo; c <= chi; ++c)
    atomicOr(&Dm[w + (c >> 6)], 1ull << (c & 63));
}

// ---------------------------------------------------------------------------
// Kernel C: per-pixel OR over 180 angles with dilated-bitmask fast path.
// Exact f32 comparison (|r_est - r_phys[r]| < mw) only on D-bit hits.
// ---------------------------------------------------------------------------
__global__ __launch_bounds__(256) void mask_kernel(
    const float* __restrict__ mwp,
    const int* __restrict__ Wp,
    const u64* __restrict__ Bm, const u64* __restrict__ Dm,
    const float* __restrict__ tbl,
    float* __restrict__ out) {
  __shared__ u64  Bl[A_ * WPA], Dl[A_ * WPA];
  __shared__ float ctl[A_], stl[A_], rpl[A_];
  __shared__ float misc[4];
  int nc  = blockIdx.y;
  int tid = threadIdx.x;
  const u64* Bg = Bm + (size_t)nc * A_ * WPA;
  const u64* Dg = Dm + (size_t)nc * A_ * WPA;
  for (int i = tid; i < A_ * WPA; i += 256) { Bl[i] = Bg[i]; Dl[i] = Dg[i]; }
  for (int i = tid; i < A_; i += 256) {
    ctl[i] = tbl[i]; stl[i] = tbl[A_ + i]; rpl[i] = tbl[2*A_ + i];
  }
  if (tid < 4) misc[tid] = tbl[3*A_ + tid];
  __syncthreads();

  float inv_drho = misc[1];
  float xc_off   = misc[2];
  float yc_off   = misc[3];
  float mw       = mwp[0];

  int p = blockIdx.x * 256 + tid;
  int W = Wp[0];
  int h = p / W;
  int w = p - h * W;
  float xcv = __fsub_rn((float)w, xc_off);   // exact
  float ycv = __fsub_rn((float)h, yc_off);

  float found = 0.0f;
  for (int a = 0; a < A_; ++a) {
    if (found == 0.0f) {
      // r_est = (xc*ct) + (yc*st), no FMA (matches XLA mul-then-add)
      float re = __fadd_rn(__fmul_rn(xcv, ctl[a]), __fmul_rn(ycv, stl[a]));
      int ci = (int)floorf(__fmaf_rn(re, inv_drho, (float)((R_-1)*0.5)));
      ci = ci < 0 ? 0 : (ci > R_ - 1 ? R_ - 1 : ci);
      u64 dmask = Dl[a * WPA + (ci >> 6)];
      if ((dmask >> (ci & 63)) & 1ull) {
        int lo = ci - 1 < 0 ? 0 : ci - 1;
        int hi = ci + 2 > R_ - 1 ? R_ - 1 : ci + 2;
        for (int r = lo; r <= hi; ++r) {
          if ((Bl[a * WPA + (r >> 6)] >> (r & 63)) & 1ull) {
            float d = __fsub_rn(re, rpl[r]);
            if (fabsf(d) < mw) { found = 1.0f; break; }
          }
        }
      }
    }
    if (__all(found != 0.0f)) break;   // whole wave done -> retire early
  }
  size_t pix_per_nc = (size_t)gridDim.x * 256;
  out[(size_t)nc * pix_per_nc + p] = found;
}

// ---------------------------------------------------------------------------
extern "C" void kernel_launch(void* const* d_in, const int* in_sizes, int n_in,
                              void* d_out, int out_size, void* d_ws, size_t ws_size,
                              hipStream_t stream) {
  const float* hm  = (const float*)d_in[0];   // [8,4,180,180] f32
  const float* mwp = (const float*)d_in[1];   // [1] f32
  const int*   Hp  = (const int*)d_in[2];     // [1] i32
  const int*   Wp  = (const int*)d_in[3];     // [1] i32
  float* out = (float*)d_out;                 // [8,4,H,W] f32

  char* base = (char*)d_ws;
  float* maxv = (float*)(base + OFF_MAX);
  u64*   Bm   = (u64*)(base + OFF_B);
  u64*   Dm   = (u64*)(base + OFF_D);
  float* tbl  = (float*)(base + OFF_TBL);

  // zero bitmask region (atomicOr accumulates; must be deterministic per call)
  hipMemsetAsync(d_ws, 0, WS_BYTES, stream);

  precompute_kernel<<<dim3(NC + 1), dim3(256), 0, stream>>>(hm, Hp, Wp, maxv, tbl);

  peaks_kernel<<<dim3((NC * AR + 255) / 256), dim3(256), 0, stream>>>(hm, maxv, Bm, Dm);

  int pix_per_nc = out_size / NC;             // H*W = 65536
  mask_kernel<<<dim3(pix_per_nc / 256, NC), dim3(256), 0, stream>>>(
      mwp, Wp, Bm, Dm, tbl, out);
}